// Round 1
// baseline (186.108 us; speedup 1.0000x reference)
//
#include <hip/hip_runtime.h>

// Reference collapses: softmax row-sums are exactly 1, and einsum 'bqk,bvd->bqd'
// contracts k and v independently, so out[b,q,d] = sum_n v[b,n,d] (q-independent).
// v = GN(x) @ Wv^T + bv  =>  sum_n v[b,n,d] = dot(Wv[d,:], colsum[b,:]) + 1024*bv[d]
// colsum[b,ch] = sum_g inv_g * pw[b,g,ch] + (sum_beta - sum_g inv_g*mean_g*sg_gamma[g])
// pw[b,g,ch] = sum_{n in group g} gamma[n] * x[b,ch,n]   (single pass over x)
// final[b,d] = dot(Wo[d,:], S[b,:]) + bo[d], broadcast over all 1024 hw positions.

#define BATCH 16
#define CH    1024      // channels of x (the 'c'/'d' dim)
#define NHW   1024      // h*w (the 'n' dim)
#define G     32        // groups
#define NPG   32        // n per group
#define EPG   (NPG*CH)  // 32768 elements per (b,g) group
#define EPSV  1e-5f

// ---- K1: per-(b,g) stats (s1, s2) + per-(b,g,ch) gamma-weighted partial sums ----
__global__ __launch_bounds__(256) void k1_stats_pw(
    const float* __restrict__ x, const float* __restrict__ gamma,
    float* __restrict__ pw, float2* __restrict__ s1s2)
{
    const int bg = blockIdx.x;            // b*32 + g, 512 blocks
    const int b  = bg >> 5, g = bg & 31;
    const int t  = threadIdx.x;
    const int n4 = t & 7;                 // which float4 of the group's 32 n's
    const int c0 = t >> 3;                // starting channel 0..31

    const float4* xg = reinterpret_cast<const float4*>(x + (size_t)b * (CH * NHW) + g * NPG);
    const float4  gm = reinterpret_cast<const float4*>(gamma + g * NPG)[n4];

    float s1 = 0.f, s2 = 0.f;
    float* pwrow = pw + (size_t)bg * CH;
    for (int ch = c0; ch < CH; ch += 32) {
        float4 v = xg[ch * (NHW / 4) + n4];
        s1 += v.x + v.y + v.z + v.w;
        s2 += v.x * v.x + v.y * v.y + v.z * v.z + v.w * v.w;
        float p = v.x * gm.x + v.y * gm.y + v.z * gm.z + v.w * gm.w;
        p += __shfl_xor(p, 1);
        p += __shfl_xor(p, 2);
        p += __shfl_xor(p, 4);
        if (n4 == 0) pwrow[ch] = p;       // unique (b,g,ch): no atomics needed
    }
    #pragma unroll
    for (int m = 1; m < 64; m <<= 1) { s1 += __shfl_xor(s1, m); s2 += __shfl_xor(s2, m); }
    __shared__ float r1[4], r2[4];
    if ((t & 63) == 0) { r1[t >> 6] = s1; r2[t >> 6] = s2; }
    __syncthreads();
    if (t == 0) s1s2[bg] = make_float2(r1[0] + r1[1] + r1[2] + r1[3],
                                       r2[0] + r2[1] + r2[2] + r2[3]);
}

// ---- K2: per-batch: group inv/mean, constant term, colsum[b,ch] ----
__global__ __launch_bounds__(256) void k2_colsum(
    const float* __restrict__ pw, const float2* __restrict__ s1s2,
    const float* __restrict__ gamma, const float* __restrict__ beta,
    float* __restrict__ colsum)
{
    const int b = blockIdx.x;             // 16 blocks
    const int t = threadIdx.x;
    __shared__ float invg[G], meang[G], sgg[G];
    __shared__ float wred[4];
    __shared__ float constb;

    if (t < G) {
        float2 s   = s1s2[b * G + t];
        float mean = s.x * (1.f / EPG);
        float var  = s.y * (1.f / EPG) - mean * mean;
        invg[t]  = rsqrtf(var + EPSV);
        meang[t] = mean;
        float sg = 0.f;
        for (int i = 0; i < NPG; i++) sg += gamma[t * NPG + i];
        sgg[t] = sg;
    }
    float bsum = beta[t] + beta[t + 256] + beta[t + 512] + beta[t + 768];
    #pragma unroll
    for (int m = 1; m < 64; m <<= 1) bsum += __shfl_xor(bsum, m);
    if ((t & 63) == 0) wred[t >> 6] = bsum;
    __syncthreads();
    if (t == 0) {
        float cb = wred[0] + wred[1] + wred[2] + wred[3];
        for (int g = 0; g < G; g++) cb -= invg[g] * meang[g] * sgg[g];
        constb = cb;
    }
    __syncthreads();
    for (int ch = t; ch < CH; ch += 256) {
        float cs = constb;
        const float* p = pw + (size_t)b * (G * CH) + ch;
        #pragma unroll 8
        for (int g = 0; g < G; g++) cs += invg[g] * p[g * CH];
        colsum[b * CH + ch] = cs;
    }
}

// ---- K3: S[b,d] = dot(Wv[d,:], colsum[b,:]) + 1024*bv[d] ; one wave per d ----
__global__ __launch_bounds__(256) void k3_matvec_v(
    const float* __restrict__ Wv, const float* __restrict__ bv,
    const float* __restrict__ colsum, float* __restrict__ S)
{
    const int t = threadIdx.x;
    const int wave = t >> 6, lane = t & 63;
    const int d = blockIdx.x * 4 + wave;  // 256 blocks * 4 waves = 1024 rows
    const float* wrow = Wv + (size_t)d * CH;
    float acc[BATCH];
    #pragma unroll
    for (int b = 0; b < BATCH; b++) acc[b] = 0.f;
    for (int e = lane; e < CH; e += 64) {
        float w = wrow[e];
        #pragma unroll
        for (int b = 0; b < BATCH; b++) acc[b] += w * colsum[b * CH + e];
    }
    #pragma unroll
    for (int b = 0; b < BATCH; b++) {
        float a = acc[b];
        #pragma unroll
        for (int m = 1; m < 64; m <<= 1) a += __shfl_xor(a, m);
        if (lane == 0) S[b * CH + d] = a + (float)NHW * bv[d];
    }
}

// ---- K4: final[b,d] = dot(Wo[d,:], S[b,:]) + bo[d]; broadcast to out[b,d,0..1023] ----
__global__ __launch_bounds__(256) void k4_final_bcast(
    const float* __restrict__ Wo, const float* __restrict__ bo,
    const float* __restrict__ S, float* __restrict__ out)
{
    const int t = threadIdx.x;
    const int wave = t >> 6, lane = t & 63;
    const int d = blockIdx.x * 4 + wave;
    const float* wrow = Wo + (size_t)d * CH;
    float acc[BATCH];
    #pragma unroll
    for (int b = 0; b < BATCH; b++) acc[b] = 0.f;
    for (int e = lane; e < CH; e += 64) {
        float w = wrow[e];
        #pragma unroll
        for (int b = 0; b < BATCH; b++) acc[b] += w * S[b * CH + e];
    }
    #pragma unroll
    for (int b = 0; b < BATCH; b++) {   // full butterfly: all lanes hold the sum
        #pragma unroll
        for (int m = 1; m < 64; m <<= 1) acc[b] += __shfl_xor(acc[b], m);
    }
    const float bod = bo[d];
    #pragma unroll
    for (int b = 0; b < BATCH; b++) {
        float val = acc[b] + bod;
        float4 v4 = make_float4(val, val, val, val);
        float4* op = reinterpret_cast<float4*>(out + ((size_t)b * CH + d) * NHW);
        #pragma unroll
        for (int i = 0; i < 4; i++) op[i * 64 + lane] = v4;  // 1024B contiguous per wave-store
    }
}

extern "C" void kernel_launch(void* const* d_in, const int* in_sizes, int n_in,
                              void* d_out, int out_size, void* d_ws, size_t ws_size,
                              hipStream_t stream)
{
    const float* x     = (const float*)d_in[0];
    const float* gamma = (const float*)d_in[1];
    const float* beta  = (const float*)d_in[2];
    // d_in[3..6] = Wq, bq, Wk, bk: provably dead (softmax row-sum == 1)
    const float* Wv    = (const float*)d_in[7];
    const float* bv    = (const float*)d_in[8];
    const float* Wo    = (const float*)d_in[9];
    const float* bo    = (const float*)d_in[10];
    float* out = (float*)d_out;

    char* ws = (char*)d_ws;
    float*  pw     = (float*)ws;                                    // 16*32*1024 f = 2 MiB
    float2* s1s2   = (float2*)(ws + (size_t)524288 * 4);            // 512 float2 = 4 KiB
    float*  colsum = (float*)(ws + (size_t)524288 * 4 + 4096);      // 16384 f = 64 KiB
    float*  Sbuf   = (float*)(ws + (size_t)524288 * 4 + 4096 + 65536); // 16384 f = 64 KiB

    k1_stats_pw   <<<BATCH * G, 256, 0, stream>>>(x, gamma, pw, s1s2);
    k2_colsum     <<<BATCH,     256, 0, stream>>>(pw, s1s2, gamma, beta, colsum);
    k3_matvec_v   <<<NHW / 4,   256, 0, stream>>>(Wv, bv, colsum, Sbuf);
    k4_final_bcast<<<NHW / 4,   256, 0, stream>>>(Wo, bo, Sbuf, out);
}

// Round 2
// 182.277 us; speedup vs baseline: 1.0210x; 1.0210x over previous
//
#include <hip/hip_runtime.h>

// Reference collapses: softmax row-sums are exactly 1, and einsum 'bqk,bvd->bqd'
// contracts k and v independently, so out[b,q,d] = sum_n v[b,n,d] (q-independent).
// v = GN(x) @ Wv^T + bv  =>  sum_n v[b,n,d] = dot(Wv[d,:], colsum[b,:]) + 1024*bv[d]
// colsum[b,ch] = sum_g inv_g * pw[b,g,ch] + (sum_beta - sum_g inv_g*mean_g*sg_gamma[g])
// pw[b,g,ch] = sum_{n in group g} gamma[n] * x[b,ch,n]   (single pass over x)
// final[b,d] = dot(Wo[d,:], S[b,:]) + bo[d], broadcast over all 1024 hw positions.

#define BATCH 16
#define CH    1024      // channels of x (the 'c'/'d' dim)
#define NHW   1024      // h*w (the 'n' dim)
#define G     32        // groups
#define NPG   32        // n per group
#define EPG   (NPG*CH)  // 32768 elements per (b,g) group
#define EPSV  1e-5f

// ---- K1: per-(b,g) stats (s1, s2) + per-(b,g,ch) gamma-weighted partial sums ----
__global__ __launch_bounds__(256) void k1_stats_pw(
    const float* __restrict__ x, const float* __restrict__ gamma,
    float* __restrict__ pw, float2* __restrict__ s1s2)
{
    const int bg = blockIdx.x;            // b*32 + g, 512 blocks
    const int b  = bg >> 5, g = bg & 31;
    const int t  = threadIdx.x;
    const int n4 = t & 7;                 // which float4 of the group's 32 n's
    const int c0 = t >> 3;                // starting channel 0..31

    const float4* xg = reinterpret_cast<const float4*>(x + (size_t)b * (CH * NHW) + g * NPG);
    const float4  gm = reinterpret_cast<const float4*>(gamma + g * NPG)[n4];

    float s1 = 0.f, s2 = 0.f;
    float* pwrow = pw + (size_t)bg * CH;
    for (int ch = c0; ch < CH; ch += 32) {
        float4 v = xg[ch * (NHW / 4) + n4];
        s1 += v.x + v.y + v.z + v.w;
        s2 += v.x * v.x + v.y * v.y + v.z * v.z + v.w * v.w;
        float p = v.x * gm.x + v.y * gm.y + v.z * gm.z + v.w * gm.w;
        p += __shfl_xor(p, 1);
        p += __shfl_xor(p, 2);
        p += __shfl_xor(p, 4);
        if (n4 == 0) pwrow[ch] = p;       // unique (b,g,ch): no atomics needed
    }
    #pragma unroll
    for (int m = 1; m < 64; m <<= 1) { s1 += __shfl_xor(s1, m); s2 += __shfl_xor(s2, m); }
    __shared__ float r1[4], r2[4];
    if ((t & 63) == 0) { r1[t >> 6] = s1; r2[t >> 6] = s2; }
    __syncthreads();
    if (t == 0) s1s2[bg] = make_float2(r1[0] + r1[1] + r1[2] + r1[3],
                                       r2[0] + r2[1] + r2[2] + r2[3]);
}

// ---- K2: colsum[b,ch] — 256 blocks (16 b x 16 chunks of 64 ch), full occupancy ----
__global__ __launch_bounds__(256) void k2_colsum(
    const float* __restrict__ pw, const float2* __restrict__ s1s2,
    const float* __restrict__ gamma, const float* __restrict__ beta,
    float* __restrict__ colsum)
{
    const int b     = blockIdx.x >> 4;    // 16 batches
    const int chunk = blockIdx.x & 15;    // 16 chunks of 64 channels
    const int t = threadIdx.x;
    __shared__ float invg[G], meang[G], sgg[G];
    __shared__ float wred[4];
    __shared__ float part[4][64];
    __shared__ float constb;

    // per-group stats (redundant per block: tiny, L3-cached)
    if (t < G) {
        float2 s   = s1s2[b * G + t];
        float mean = s.x * (1.f / EPG);
        float var  = s.y * (1.f / EPG) - mean * mean;
        invg[t]  = rsqrtf(var + EPSV);
        meang[t] = mean;
        float sg = 0.f;
        for (int i = 0; i < NPG; i++) sg += gamma[t * NPG + i];
        sgg[t] = sg;
    }
    float bsum = beta[t] + beta[t + 256] + beta[t + 512] + beta[t + 768];
    #pragma unroll
    for (int m = 1; m < 64; m <<= 1) bsum += __shfl_xor(bsum, m);
    if ((t & 63) == 0) wred[t >> 6] = bsum;
    __syncthreads();
    if (t == 0) {
        float cb = wred[0] + wred[1] + wred[2] + wred[3];
        for (int g = 0; g < G; g++) cb -= invg[g] * meang[g] * sgg[g];
        constb = cb;
    }
    // partial reduction over groups: 4 thread-teams x 64 channels, 8 groups each
    const int chl = t & 63;               // channel within chunk
    const int gq  = t >> 6;               // group-quarter 0..3
    const float* p = pw + (size_t)b * (G * CH) + chunk * 64 + chl;
    float acc = 0.f;
    #pragma unroll
    for (int i = 0; i < 8; i++) {
        int g = gq * 8 + i;
        acc += invg[g] * p[(size_t)g * CH];
    }
    part[gq][chl] = acc;
    __syncthreads();
    if (t < 64) {
        float cs = constb + part[0][t] + part[1][t] + part[2][t] + part[3][t];
        colsum[b * CH + chunk * 64 + t] = cs;
    }
}

// ---- K3: S[b,d] = dot(Wv[d,:], colsum[b,:]) + 1024*bv[d] ; one wave per d ----
__global__ __launch_bounds__(256) void k3_matvec_v(
    const float* __restrict__ Wv, const float* __restrict__ bv,
    const float* __restrict__ colsum, float* __restrict__ S)
{
    const int t = threadIdx.x;
    const int wave = t >> 6, lane = t & 63;
    const int d = blockIdx.x * 4 + wave;  // 256 blocks * 4 waves = 1024 rows
    const float* wrow = Wv + (size_t)d * CH;
    float acc[BATCH];
    #pragma unroll
    for (int b = 0; b < BATCH; b++) acc[b] = 0.f;
    for (int e = lane; e < CH; e += 64) {
        float w = wrow[e];
        #pragma unroll
        for (int b = 0; b < BATCH; b++) acc[b] += w * colsum[b * CH + e];
    }
    #pragma unroll
    for (int b = 0; b < BATCH; b++) {
        float a = acc[b];
        #pragma unroll
        for (int m = 1; m < 64; m <<= 1) a += __shfl_xor(a, m);
        if (lane == 0) S[b * CH + d] = a + (float)NHW * bv[d];
    }
}

// ---- K4: final[b,d] = dot(Wo[d,:], S[b,:]) + bo[d]; broadcast to out[b,d,0..1023] ----
__global__ __launch_bounds__(256) void k4_final_bcast(
    const float* __restrict__ Wo, const float* __restrict__ bo,
    const float* __restrict__ S, float* __restrict__ out)
{
    const int t = threadIdx.x;
    const int wave = t >> 6, lane = t & 63;
    const int d = blockIdx.x * 4 + wave;
    const float* wrow = Wo + (size_t)d * CH;
    float acc[BATCH];
    #pragma unroll
    for (int b = 0; b < BATCH; b++) acc[b] = 0.f;
    for (int e = lane; e < CH; e += 64) {
        float w = wrow[e];
        #pragma unroll
        for (int b = 0; b < BATCH; b++) acc[b] += w * S[b * CH + e];
    }
    #pragma unroll
    for (int b = 0; b < BATCH; b++) {   // full butterfly: all lanes hold the sum
        #pragma unroll
        for (int m = 1; m < 64; m <<= 1) acc[b] += __shfl_xor(acc[b], m);
    }
    const float bod = bo[d];
    #pragma unroll
    for (int b = 0; b < BATCH; b++) {
        float val = acc[b] + bod;
        float4 v4 = make_float4(val, val, val, val);
        float4* op = reinterpret_cast<float4*>(out + ((size_t)b * CH + d) * NHW);
        #pragma unroll
        for (int i = 0; i < 4; i++) op[i * 64 + lane] = v4;  // 1024B contiguous per wave-store
    }
}

extern "C" void kernel_launch(void* const* d_in, const int* in_sizes, int n_in,
                              void* d_out, int out_size, void* d_ws, size_t ws_size,
                              hipStream_t stream)
{
    const float* x     = (const float*)d_in[0];
    const float* gamma = (const float*)d_in[1];
    const float* beta  = (const float*)d_in[2];
    // d_in[3..6] = Wq, bq, Wk, bk: provably dead (softmax row-sum == 1)
    const float* Wv    = (const float*)d_in[7];
    const float* bv    = (const float*)d_in[8];
    const float* Wo    = (const float*)d_in[9];
    const float* bo    = (const float*)d_in[10];
    float* out = (float*)d_out;

    char* ws = (char*)d_ws;
    float*  pw     = (float*)ws;                                    // 16*32*1024 f = 2 MiB
    float2* s1s2   = (float2*)(ws + (size_t)524288 * 4);            // 512 float2 = 4 KiB
    float*  colsum = (float*)(ws + (size_t)524288 * 4 + 4096);      // 16384 f = 64 KiB
    float*  Sbuf   = (float*)(ws + (size_t)524288 * 4 + 4096 + 65536); // 16384 f = 64 KiB

    k1_stats_pw   <<<BATCH * G, 256, 0, stream>>>(x, gamma, pw, s1s2);
    k2_colsum     <<<BATCH * 16, 256, 0, stream>>>(pw, s1s2, gamma, beta, colsum);
    k3_matvec_v   <<<NHW / 4,   256, 0, stream>>>(Wv, bv, colsum, Sbuf);
    k4_final_bcast<<<NHW / 4,   256, 0, stream>>>(Wo, bo, Sbuf, out);
}

// Round 4
// 178.988 us; speedup vs baseline: 1.0398x; 1.0184x over previous
//
#include <hip/hip_runtime.h>

// Reference collapses: softmax row-sums are exactly 1, and einsum 'bqk,bvd->bqd'
// contracts k and v independently, so out[b,q,d] = sum_n v[b,n,d] (q-independent).
//   colsum[b,ch] = sum_n GN(x)[b,n,ch]  (computed in K1 via per-group atomics)
//   S[b,d]   = dot(Wv[d,:], colsum[b,:]) + 1024*bv[d]                      (K3)
//   out[b,d,0..1023] = dot(Wo[d,:], S[b,:]) + bo[d]  broadcast over hw     (K4)
// Wq/bq/Wk/bk are provably dead (they only enter via softmax row-sum == 1).
// K1 fuses GroupNorm stats + colsum: block (b,g) owns ALL data of group (b,g),
// so it computes mean/var/inv locally and atomicAdds inv*pw[ch] + cshare into
// colsum, where cshare = sum_beta/32 - inv*mean*sum_gamma_g (sums exactly to
// the GN constant over the 32 g-blocks). No pw round-trip, no k2 dispatch.

#define BATCH 16
#define CH    1024
#define NHW   1024
#define G     32
#define NPG   32
#define EPG   (NPG*CH)
#define EPSV  1e-5f

// ---- K1: fused stats + colsum contribution (512 blocks = 16 b x 32 g) ----
__global__ __launch_bounds__(256) void k1_fused(
    const float* __restrict__ x, const float* __restrict__ gamma,
    const float* __restrict__ beta, float* __restrict__ colsum)
{
    const int bg = blockIdx.x;            // b*32 + g
    const int b  = bg >> 5, g = bg & 31;
    const int t  = threadIdx.x;
    const int lane = t & 63, wave = t >> 6;
    const int n4 = t & 7;                 // which float4 of the group's 32 n's
    const int c0 = t >> 3;                // starting channel 0..31

    __shared__ float pch[CH];             // gamma-weighted per-channel partials
    __shared__ float r1[4], r2[4], rb[4];

    const float4* xg = reinterpret_cast<const float4*>(x + (size_t)b * (CH * NHW) + g * NPG);
    const float4  gm = reinterpret_cast<const float4*>(gamma + g * NPG)[n4];

    float s1 = 0.f, s2 = 0.f;
    for (int ch = c0; ch < CH; ch += 32) {
        float4 v = xg[ch * (NHW / 4) + n4];
        s1 += v.x + v.y + v.z + v.w;
        s2 += v.x * v.x + v.y * v.y + v.z * v.z + v.w * v.w;
        float p = v.x * gm.x + v.y * gm.y + v.z * gm.z + v.w * gm.w;
        p += __shfl_xor(p, 1);
        p += __shfl_xor(p, 2);
        p += __shfl_xor(p, 4);
        if (n4 == 0) pch[ch] = p;         // one writer per 8-lane cluster
    }
    // sum of beta (same in every block; L3-cached 4 KiB)
    float bsum = beta[t] + beta[t + 256] + beta[t + 512] + beta[t + 768];
    #pragma unroll
    for (int m = 1; m < 64; m <<= 1) {
        s1 += __shfl_xor(s1, m); s2 += __shfl_xor(s2, m); bsum += __shfl_xor(bsum, m);
    }
    if (lane == 0) { r1[wave] = s1; r2[wave] = s2; rb[wave] = bsum; }
    __syncthreads();

    const float S1 = r1[0] + r1[1] + r1[2] + r1[3];
    const float S2 = r2[0] + r2[1] + r2[2] + r2[3];
    const float SB = rb[0] + rb[1] + rb[2] + rb[3];
    const float mean = S1 * (1.f / EPG);
    const float var  = S2 * (1.f / EPG) - mean * mean;
    const float inv  = rsqrtf(var + EPSV);
    // sum of this group's 32 gammas (from the per-lane float4, butterfly over n4)
    float sg = gm.x + gm.y + gm.z + gm.w;
    sg += __shfl_xor(sg, 1);
    sg += __shfl_xor(sg, 2);
    sg += __shfl_xor(sg, 4);
    const float cshare = SB * (1.f / 32.f) - inv * mean * sg;

    for (int ch = t; ch < CH; ch += 256)
        atomicAdd(&colsum[b * CH + ch], inv * pch[ch] + cshare);
}

// ---- K3: S[b,d] = dot(Wv[d,:], colsum[b,:]) + 1024*bv[d]; one wave per d ----
__global__ __launch_bounds__(256) void k3_matvec_v(
    const float* __restrict__ Wv, const float* __restrict__ bv,
    const float* __restrict__ colsum, float* __restrict__ S)
{
    const int t = threadIdx.x;
    const int wave = t >> 6, lane = t & 63;
    const int d = blockIdx.x * 4 + wave;  // 256 blocks * 4 waves = 1024 rows
    const float4* wrow = reinterpret_cast<const float4*>(Wv + (size_t)d * CH);
    const float4* cs4  = reinterpret_cast<const float4*>(colsum);
    float acc[BATCH];
    #pragma unroll
    for (int b = 0; b < BATCH; b++) acc[b] = 0.f;
    #pragma unroll
    for (int i = 0; i < 4; i++) {
        int e4 = i * 64 + lane;
        float4 w = wrow[e4];
        #pragma unroll
        for (int b = 0; b < BATCH; b++) {
            float4 c = cs4[b * 256 + e4];
            acc[b] += w.x * c.x + w.y * c.y + w.z * c.z + w.w * c.w;
        }
    }
    #pragma unroll
    for (int b = 0; b < BATCH; b++) {
        float a = acc[b];
        #pragma unroll
        for (int m = 1; m < 64; m <<= 1) a += __shfl_xor(a, m);
        if (lane == 0) S[b * CH + d] = a + (float)NHW * bv[d];
    }
}

// ---- K4: out[b,d,:] = dot(Wo[d,:], S[b,:]) + bo[d], broadcast over 1024 hw ----
__global__ __launch_bounds__(256) void k4_final_bcast(
    const float* __restrict__ Wo, const float* __restrict__ bo,
    const float* __restrict__ S, float* __restrict__ out)
{
    const int t = threadIdx.x;
    const int wave = t >> 6, lane = t & 63;
    const int d = blockIdx.x * 4 + wave;
    const float4* wrow = reinterpret_cast<const float4*>(Wo + (size_t)d * CH);
    const float4* s4   = reinterpret_cast<const float4*>(S);
    float acc[BATCH];
    #pragma unroll
    for (int b = 0; b < BATCH; b++) acc[b] = 0.f;
    #pragma unroll
    for (int i = 0; i < 4; i++) {
        int e4 = i * 64 + lane;
        float4 w = wrow[e4];
        #pragma unroll
        for (int b = 0; b < BATCH; b++) {
            float4 c = s4[b * 256 + e4];
            acc[b] += w.x * c.x + w.y * c.y + w.z * c.z + w.w * c.w;
        }
    }
    #pragma unroll
    for (int b = 0; b < BATCH; b++) {     // full butterfly: all lanes hold the sum
        #pragma unroll
        for (int m = 1; m < 64; m <<= 1) acc[b] += __shfl_xor(acc[b], m);
    }
    const float bod = bo[d];
    #pragma unroll
    for (int b = 0; b < BATCH; b++) {
        float val = acc[b] + bod;
        float4 v4 = make_float4(val, val, val, val);
        float4* op = reinterpret_cast<float4*>(out + ((size_t)b * CH + d) * NHW);
        #pragma unroll
        for (int i = 0; i < 4; i++) op[i * 64 + lane] = v4;  // 1 KiB contiguous per wave-store
    }
}

extern "C" void kernel_launch(void* const* d_in, const int* in_sizes, int n_in,
                              void* d_out, int out_size, void* d_ws, size_t ws_size,
                              hipStream_t stream)
{
    const float* x     = (const float*)d_in[0];
    const float* gamma = (const float*)d_in[1];
    const float* beta  = (const float*)d_in[2];
    // d_in[3..6] = Wq, bq, Wk, bk: provably dead (softmax row-sum == 1)
    const float* Wv    = (const float*)d_in[7];
    const float* bv    = (const float*)d_in[8];
    const float* Wo    = (const float*)d_in[9];
    const float* bo    = (const float*)d_in[10];
    float* out = (float*)d_out;

    char* ws = (char*)d_ws;
    float* colsum = (float*)ws;                       // 16*1024 f = 64 KiB
    float* Sbuf   = (float*)(ws + 65536);             // 16*1024 f = 64 KiB

    hipMemsetAsync(colsum, 0, BATCH * CH * sizeof(float), stream);
    k1_fused      <<<BATCH * G, 256, 0, stream>>>(x, gamma, beta, colsum);
    k3_matvec_v   <<<NHW / 4,   256, 0, stream>>>(Wv, bv, colsum, Sbuf);
    k4_final_bcast<<<NHW / 4,   256, 0, stream>>>(Wo, bo, Sbuf, out);
}